// Round 2
// baseline (665.282 us; speedup 1.0000x reference)
//
#include <hip/hip_runtime.h>
#include <math.h>

#define D 256
#define BLOCK 256
#define WPB 4            // waves per block
#define R 4              // rows per chunk
// 3-deep chunk pipeline: compute t while t+1, t+2 in flight (never vmcnt(0))

typedef float f32x4 __attribute__((ext_vector_type(4)));

// Pass 1: segment bounds. starts[s] = lower_bound(batch, s), starts[B] = N.
__global__ void seg_bounds_kernel(const int* __restrict__ batch,
                                  int* __restrict__ starts, int N, int B)
{
    int i = blockIdx.x * blockDim.x + threadIdx.x;
    const int stride = gridDim.x * blockDim.x;
    for (; i < N; i += stride) {
        const int cur  = batch[i];
        const int prev = (i == 0) ? -1 : batch[i - 1];
        for (int s = prev + 1; s <= cur; ++s) starts[s] = i;
        if (i == N - 1)
            for (int s = cur + 1; s <= B; ++s) starts[s] = N;
    }
}

// Pass 2: ONE WAVE PER SEGMENT. 1024 blocks x 4 waves = 4096 waves, entire
// grid co-resident (4 blocks/CU). Each wave streams its segment's rows
// (64 lanes x float4 = 1 KB/row, coalesced) through a 3-deep register
// pipeline with wave-uniform (SGPR) base addressing; online softmax is
// per-wave start to finish: no LDS, no __syncthreads, no inter-wave merge.
__global__ __launch_bounds__(BLOCK, 4) void niche_attn_kernel(
    const float* __restrict__ x,
    const float* __restrict__ w,
    const float* __restrict__ bptr,
    const int*   __restrict__ starts,
    float*       __restrict__ out, int B)
{
    int seg = blockIdx.x * WPB + (threadIdx.x >> 6);
    seg = __builtin_amdgcn_readfirstlane(seg);   // wave-uniform -> scalar loads
    if (seg >= B) return;

    const int lane = threadIdx.x & 63;
    const int col  = lane << 2;                  // this lane's 4 columns

    const int row_start = starts[seg];
    const int row_end   = starts[seg + 1];
    float* outp = out + (size_t)seg * D;

    if (row_end <= row_start) {                  // empty segment -> zeros
        f32x4 z = {0.f, 0.f, 0.f, 0.f};
        *(f32x4*)(outp + col) = z;
        return;
    }

    const f32x4 w4   = *(const f32x4*)(w + col);
    const float bias = *bptr;

    float m = -INFINITY, l = 0.f;
    f32x4 acc = {0.f, 0.f, 0.f, 0.f};

    const int len   = row_end - row_start;
    const int nfull = len >> 2;                  // full chunks of R=4 rows
    const int rem   = len & 3;

    const float* sbase = x + (size_t)row_start * D;   // wave-uniform base

    // Chunk t = rows [4t, 4t+4): 4 loads off one scalar base, imm offsets
    // 0/1024/2048/3072 B. Per-chunk address cost: one scalar pointer bump.
    auto loadchunk = [&](f32x4* buf, int t) {
        const float* p = sbase + (size_t)t * (R * D) + col;
#pragma unroll
        for (int i = 0; i < R; ++i)
            buf[i] = *(const f32x4*)(p + i * D);
    };

    // R dots + interleaved butterflies + one branchless online-softmax
    // update. 'valid' is R at full-chunk call sites (folds away after
    // inlining) and rem at the tail call site (masks dup rows to -inf).
    auto computec = [&](const f32x4* buf, int valid) {
        float s[R];
#pragma unroll
        for (int i = 0; i < R; ++i) {
            float t0 = buf[i].x * w4.x;
            t0   = fmaf(buf[i].y, w4.y, t0);
            t0   = fmaf(buf[i].z, w4.z, t0);
            s[i] = fmaf(buf[i].w, w4.w, t0);
        }
#pragma unroll
        for (int off = 32; off > 0; off >>= 1) {
#pragma unroll
            for (int i = 0; i < R; ++i)
                s[i] += __shfl_xor(s[i], off, 64);
        }
#pragma unroll
        for (int i = 0; i < R; ++i)
            s[i] = (i < valid) ? (s[i] + bias) : -INFINITY;

        const float cmax = fmaxf(fmaxf(s[0], s[1]), fmaxf(s[2], s[3]));
        const float newm = fmaxf(m, cmax);       // first iter: m=-inf
        const float alpha = __expf(m - newm);    // -> alpha = 0
        float p[R];
#pragma unroll
        for (int i = 0; i < R; ++i)
            p[i] = __expf(s[i] - newm);
        l = l * alpha + ((p[0] + p[1]) + (p[2] + p[3]));
        acc.x *= alpha; acc.y *= alpha; acc.z *= alpha; acc.w *= alpha;
#pragma unroll
        for (int i = 0; i < R; ++i) {
            acc.x = fmaf(buf[i].x, p[i], acc.x);
            acc.y = fmaf(buf[i].y, p[i], acc.y);
            acc.z = fmaf(buf[i].z, p[i], acc.z);
            acc.w = fmaf(buf[i].w, p[i], acc.w);
        }
        m = newm;
    };

    f32x4 bufA[R], bufB[R], bufC[R];

    if (nfull > 0) {
        // Prologue: fill the pipeline (clamped indices -> harmless dups).
        const int c1 = (1 < nfull) ? 1 : nfull - 1;
        const int c2 = (2 < nfull) ? 2 : nfull - 1;
        loadchunk(bufA, 0);
        loadchunk(bufB, c1);
        loadchunk(bufC, c2);
        // Steady state: slot serving chunk t is reloaded with chunk t+3
        // (scalar-clamped; loads past nfull-1 are dups that are never
        // computed and hit L2). Static 3-way rotation keeps all buffer
        // indexing compile-time (no scratch).
        int t = 0;
        for (;;) {
            computec(bufA, R);
            if (++t == nfull) break;
            { int tp = t + 2; tp = (tp < nfull) ? tp : (nfull - 1); loadchunk(bufA, tp); }
            computec(bufB, R);
            if (++t == nfull) break;
            { int tp = t + 2; tp = (tp < nfull) ? tp : (nfull - 1); loadchunk(bufB, tp); }
            computec(bufC, R);
            if (++t == nfull) break;
            { int tp = t + 2; tp = (tp < nfull) ? tp : (nfull - 1); loadchunk(bufC, tp); }
        }
    }

    if (rem) {                                   // masked tail (1..3 rows)
        f32x4 tb[R];
        const int base_r = nfull * R;
        const int last   = len - 1;
#pragma unroll
        for (int i = 0; i < R; ++i) {
            int r = base_r + i; r = (r <= last) ? r : last;
            tb[i] = *(const f32x4*)(sbase + (size_t)r * D + col);
        }
        computec(tb, rem);
    }

    const float invL = 1.f / l;
    f32x4 o;
    o.x = acc.x * invL; o.y = acc.y * invL;
    o.z = acc.z * invL; o.w = acc.w * invL;
    *(f32x4*)(outp + col) = o;
}

extern "C" void kernel_launch(void* const* d_in, const int* in_sizes, int n_in,
                              void* d_out, int out_size, void* d_ws, size_t ws_size,
                              hipStream_t stream)
{
    const float* x      = (const float*)d_in[0];
    const float* w      = (const float*)d_in[1];
    const float* b      = (const float*)d_in[2];
    const int*   batch  = (const int*)d_in[3];
    float*       out    = (float*)d_out;
    int*         starts = (int*)d_ws;    // (B+1) ints

    const int N = in_sizes[3];           // batch[] length
    const int B = out_size / D;          // num_segments (4096)

    seg_bounds_kernel<<<1024, BLOCK, 0, stream>>>(batch, starts, N, B);
    niche_attn_kernel<<<(B + WPB - 1) / WPB, BLOCK, 0, stream>>>(
        x, w, b, starts, out, B);
}

// Round 5
// 664.870 us; speedup vs baseline: 1.0006x; 1.0006x over previous
//
#include <hip/hip_runtime.h>
#include <math.h>

#define D 256
#define BLOCK 256
#define WPB 4            // waves per block
#define R 4              // rows per chunk

typedef float f32x4 __attribute__((ext_vector_type(4)));

// DPP move on the VALU pipe (no DS pipe). Only plain quad_perm controls:
//   0xB1 = quad_perm{1,0,3,2}  -> lane ^ 1
//   0x4E = quad_perm{2,3,0,1}  -> lane ^ 2
template<int CTRL>
__device__ __forceinline__ float dpp_mov_f(float v) {
    return __int_as_float(__builtin_amdgcn_update_dpp(
        0, __float_as_int(v), CTRL, 0xF, 0xF, true));
}

// Pass 1: segment bounds. starts[s] = lower_bound(batch, s), starts[B] = N.
__global__ void seg_bounds_kernel(const int* __restrict__ batch,
                                  int* __restrict__ starts, int N, int B)
{
    int i = blockIdx.x * blockDim.x + threadIdx.x;
    const int stride = gridDim.x * blockDim.x;
    for (; i < N; i += stride) {
        const int cur  = batch[i];
        const int prev = (i == 0) ? -1 : batch[i - 1];
        for (int s = prev + 1; s <= cur; ++s) starts[s] = i;
        if (i == N - 1)
            for (int s = cur + 1; s <= B; ++s) starts[s] = N;
    }
}

// Pass 2: one wave per segment (4096 waves, whole grid co-resident).
// Per 4-row chunk: fold rows pairwise with quad_perm DPP so lane l carries
// the quad-partial of row l&3; ONE shared 4-step xor butterfly (DS pipe:
// 4 ops vs 24 in the per-row version); ONE exp per chunk instead of 4;
// 3 DPP + 8 selects gather the 4 p-values back to row order for the fmas.
__global__ __launch_bounds__(BLOCK, 4) void niche_attn_kernel(
    const float* __restrict__ x,
    const float* __restrict__ w,
    const float* __restrict__ bptr,
    const int*   __restrict__ starts,
    float*       __restrict__ out, int B)
{
    int seg = blockIdx.x * WPB + (threadIdx.x >> 6);
    seg = __builtin_amdgcn_readfirstlane(seg);   // wave-uniform -> scalar base
    if (seg >= B) return;

    const int lane = threadIdx.x & 63;
    const int col  = lane << 2;

    const int row_start = starts[seg];
    const int row_end   = starts[seg + 1];
    float* outp = out + (size_t)seg * D;

    if (row_end <= row_start) {                  // empty segment -> zeros
        f32x4 z = {0.f, 0.f, 0.f, 0.f};
        *(f32x4*)(outp + col) = z;
        return;
    }

    const f32x4 w4   = *(const f32x4*)(w + col);
    const float bias = *bptr;

    float m = -INFINITY, l = 0.f;
    f32x4 acc = {0.f, 0.f, 0.f, 0.f};

    const int len   = row_end - row_start;
    const int nfull = len >> 2;
    const int rem   = len & 3;

    const float* sbase = x + (size_t)row_start * D;

    auto loadchunk = [&](f32x4* buf, int t) {
        const float* p = sbase + (size_t)t * (R * D) + col;
#pragma unroll
        for (int i = 0; i < R; ++i)
            buf[i] = *(const f32x4*)(p + i * D);
    };

    const bool b0 = (lane & 1) != 0;
    const bool b1 = (lane & 2) != 0;
    const int  krow = lane & 3;

    auto computec = [&](const f32x4* buf, int valid) {
        float s[R];
#pragma unroll
        for (int i = 0; i < R; ++i) {
            float t0 = buf[i].x * w4.x;
            t0   = fmaf(buf[i].y, w4.y, t0);
            t0   = fmaf(buf[i].z, w4.z, t0);
            s[i] = fmaf(buf[i].w, w4.w, t0);
        }
        // fold A (xor1, DPP): even lanes keep rows 0/2, odd rows 1/3
        float a01 = b0 ? s[1] : s[0];
        float v01 = b0 ? s[0] : s[1];
        a01 += dpp_mov_f<0xB1>(v01);
        float a23 = b0 ? s[3] : s[2];
        float v23 = b0 ? s[2] : s[3];
        a23 += dpp_mov_f<0xB1>(v23);
        // fold B (xor2, DPP): lane l now carries quad-partial of row l&3
        float c = b1 ? a23 : a01;
        float d = b1 ? a01 : a23;
        c += dpp_mov_f<0x4E>(d);
        // ONE shared butterfly over bits 2..5 (row index l&3 preserved):
        c += __shfl_xor(c, 4, 64);
        c += __shfl_xor(c, 8, 64);
        c += __shfl_xor(c, 16, 64);
        c += __shfl_xor(c, 32, 64);
        // c = full 64-lane score of row (l&3)
        float sf = (krow < valid) ? (c + bias) : -INFINITY;
        // chunk max over the 4 rows (each quad holds all 4)
        float t1   = fmaxf(sf, dpp_mov_f<0xB1>(sf));
        float cmax = fmaxf(t1, dpp_mov_f<0x4E>(t1));
        const float newm  = fmaxf(m, cmax);     // first chunk: m=-inf
        const float alpha = __expf(m - newm);   //  -> alpha=0
        float p = __expf(sf - newm);            // ONE exp per chunk
        // sum of p over the 4 rows
        float u    = p + dpp_mov_f<0xB1>(p);
        float sum4 = u + dpp_mov_f<0x4E>(u);
        l = l * alpha + sum4;
        // gather all 4 rows' p per lane (3 DPP + 8 selects)
        float pn1 = dpp_mov_f<0xB1>(p);         // row (l&3)^1
        float pn2 = dpp_mov_f<0x4E>(p);         // row (l&3)^2
        float pn3 = dpp_mov_f<0xB1>(pn2);       // row (l&3)^3
        float A0 = b0 ? pn1 : p,   A1 = b0 ? p   : pn1;
        float A2 = b0 ? pn3 : pn2, A3 = b0 ? pn2 : pn3;
        float q0 = b1 ? A2 : A0;                // p of row 0
        float q1 = b1 ? A3 : A1;                // p of row 1
        float q2 = b1 ? A0 : A2;                // p of row 2
        float q3 = b1 ? A1 : A3;                // p of row 3
        acc.x *= alpha; acc.y *= alpha; acc.z *= alpha; acc.w *= alpha;
        acc.x = fmaf(buf[0].x, q0, acc.x); acc.y = fmaf(buf[0].y, q0, acc.y);
        acc.z = fmaf(buf[0].z, q0, acc.z); acc.w = fmaf(buf[0].w, q0, acc.w);
        acc.x = fmaf(buf[1].x, q1, acc.x); acc.y = fmaf(buf[1].y, q1, acc.y);
        acc.z = fmaf(buf[1].z, q1, acc.z); acc.w = fmaf(buf[1].w, q1, acc.w);
        acc.x = fmaf(buf[2].x, q2, acc.x); acc.y = fmaf(buf[2].y, q2, acc.y);
        acc.z = fmaf(buf[2].z, q2, acc.z); acc.w = fmaf(buf[2].w, q2, acc.w);
        acc.x = fmaf(buf[3].x, q3, acc.x); acc.y = fmaf(buf[3].y, q3, acc.y);
        acc.z = fmaf(buf[3].z, q3, acc.z); acc.w = fmaf(buf[3].w, q3, acc.w);
        m = newm;
    };

    f32x4 bA[R], bB[R], bC[R];

    if (nfull > 0) {
        // 3-deep pipeline: compute t with t+1, t+2 in flight (12 loads/wave).
        const int c1 = (1 < nfull) ? 1 : nfull - 1;
        const int c2 = (2 < nfull) ? 2 : nfull - 1;
        loadchunk(bA, 0); loadchunk(bB, c1); loadchunk(bC, c2);
        int t = 0;
        for (;;) {
            computec(bA, R);
            if (++t == nfull) break;
            { int tp = t + 2; tp = (tp < nfull) ? tp : (nfull - 1); loadchunk(bA, tp); }
            computec(bB, R);
            if (++t == nfull) break;
            { int tp = t + 2; tp = (tp < nfull) ? tp : (nfull - 1); loadchunk(bB, tp); }
            computec(bC, R);
            if (++t == nfull) break;
            { int tp = t + 2; tp = (tp < nfull) ? tp : (nfull - 1); loadchunk(bC, tp); }
        }
    }

    if (rem) {                                   // masked tail (1..3 rows)
        f32x4 tb[R];
        const int base_r = nfull * R;
        const int last   = len - 1;
#pragma unroll
        for (int i = 0; i < R; ++i) {
            int r = base_r + i; r = (r <= last) ? r : last;
            tb[i] = *(const f32x4*)(sbase + (size_t)r * D + col);
        }
        computec(tb, rem);
    }

    const float invL = 1.f / l;
    f32x4 o;
    o.x = acc.x * invL; o.y = acc.y * invL;
    o.z = acc.z * invL; o.w = acc.w * invL;
    *(f32x4*)(outp + col) = o;
}

extern "C" void kernel_launch(void* const* d_in, const int* in_sizes, int n_in,
                              void* d_out, int out_size, void* d_ws, size_t ws_size,
                              hipStream_t stream)
{
    const float* x      = (const float*)d_in[0];
    const float* w      = (const float*)d_in[1];
    const float* b      = (const float*)d_in[2];
    const int*   batch  = (const int*)d_in[3];
    float*       out    = (float*)d_out;
    int*         starts = (int*)d_ws;    // (B+1) ints

    const int N = in_sizes[3];           // batch[] length
    const int B = out_size / D;          // num_segments (4096)

    seg_bounds_kernel<<<1024, BLOCK, 0, stream>>>(batch, starts, N, B);
    niche_attn_kernel<<<(B + WPB - 1) / WPB, BLOCK, 0, stream>>>(
        x, w, b, starts, out, B);
}